// Round 11
// baseline (457.626 us; speedup 1.0000x reference)
//
#include <hip/hip_runtime.h>
#include <hip/hip_bf16.h>
#include <cstdint>

#define DI __device__ __forceinline__

typedef __attribute__((ext_vector_type(4))) float f32x4;
typedef __attribute__((ext_vector_type(8))) short bf16x8;

static constexpr int B_ = 16384, I_ = 1024, H_ = 1024;
static constexpr int M = B_;          // 16384 rows
static constexpr int N = 4 * H_;      // 4096 gate-cols (permuted: see cvt)
static constexpr int K = I_ + H_;     // 2048 ([x | h])
static constexpr int NT = K / 64;     // 32 K-tiles

// workspace layout (bytes)
static constexpr size_t OFF_A  = 0;                         // M*K bf16   (64 MB)
static constexpr size_t OFF_W  = OFF_A + (size_t)M * K * 2; // N*K bf16   (16 MB)
static constexpr size_t OFF_BI = OFF_W + (size_t)N * K * 2; // N f32      (16 KB)

DI unsigned short f2bf(float f) {
    union { float f; unsigned u; } v; v.f = f;
    unsigned r = v.u + 0x7FFFu + ((v.u >> 16) & 1u);
    return (unsigned short)(r >> 16);
}

// ---------------------------------------------------------------- convert
// A' = [x | h] (M x K) bf16. W' rows PERMUTED so that GEMM col
// r = g64*64 + gate*16 + l15 maps to (gate, hcol = g64*16 + l15).
__global__ void cvt_kernel(const float* __restrict__ x, const float* __restrict__ h,
                           const float* __restrict__ Wx, const float* __restrict__ Wh,
                           unsigned short* __restrict__ A, unsigned short* __restrict__ W)
{
    long tid = (long)blockIdx.x * blockDim.x + threadIdx.x;
    long row = tid >> 9;
    int  col = (int)(tid & 511) * 4;
    const float* src;
    unsigned short* dst;
    if (row < M) {
        src = (col < I_) ? x + (size_t)row * I_ + col
                         : h + (size_t)row * H_ + (col - I_);
        dst = A + (size_t)row * K + col;
    } else {
        int r = (int)(row - M);                 // dst row in W'
        int gate = (r >> 4) & 3;
        int hcol = ((r >> 6) << 4) | (r & 15);
        int srow = gate * H_ + hcol;            // src row in [4,H] stack
        src = (col < I_) ? Wx + (size_t)srow * I_ + col
                         : Wh + (size_t)srow * H_ + (col - I_);
        dst = W + (size_t)r * K + col;
    }
    float4 v = *(const float4*)src;
    ushort4 o;
    o.x = f2bf(v.x); o.y = f2bf(v.y); o.z = f2bf(v.z); o.w = f2bf(v.w);
    *(ushort4*)dst = o;
}

__global__ void bias_kernel(const float* __restrict__ bx, const float* __restrict__ bh,
                            float* __restrict__ bias)
{
    int r = blockIdx.x * blockDim.x + threadIdx.x;
    if (r < N) {
        int gate = (r >> 4) & 3;
        int hcol = ((r >> 6) << 4) | (r & 15);
        int s = gate * H_ + hcol;
        bias[r] = bx[s] + bh[s];
    }
}

// ---------------------------------------------------------------- GEMM 256x256
// PIPE-SPLIT operands: A staged via global_load_lds into swizzled LDS
// (64 KB, double-buffered) and read as ds_read_b128; B fragments loaded
// DIRECTLY global->register (plain loads; B is L2-resident: 2 MB/XCD with
// the partitioned mapping). LDS pipe load/tile drops ~2816 -> ~1550 cy, and
// VMEM / LDS / MFMA pipes can overlap instead of the measured serial sum.
// One barrier per K-tile; compiler-scheduled body; tile-end vmcnt(0)
// pre-barrier publishes the A-staging (issued a full tile earlier).
DI void stage_half(const unsigned short* __restrict__ g, int grow0, int kcol,
                   unsigned short* ldsbase, int tid)
{
    const int w    = tid >> 6, lane = tid & 63;
    const int rsub = (w << 3) + (lane >> 3);
    const int kk   = kcol + (((lane & 7) ^ (lane >> 3)) << 3);  // inverse-swizzled src
#pragma unroll
    for (int l = 0; l < 2; ++l) {
        const unsigned short* gp = g + (size_t)(grow0 + (l << 6) + rsub) * K + kk;
        unsigned short* lp = ldsbase + (((l << 6) + (w << 3)) << 6);
        __builtin_amdgcn_global_load_lds(
            (const __attribute__((address_space(1))) void*)gp,
            (__attribute__((address_space(3))) void*)lp, 16, 0, 0);
    }
}

DI bf16x8 ldfrag(const unsigned short* tile, int row, int ks, int lane)
{
    const int sl = ((ks << 2) + (lane >> 4)) ^ (lane & 7);
    return *(const bf16x8*)(tile + (row << 6) + (sl << 3));
}

DI float sigf(float v) { return 1.f / (1.f + __expf(-v)); }
DI float tanhfast(float v) {
    float vc = fminf(fmaxf(v, -15.f), 15.f);
    float e  = __expf(2.f * vc);
    return (e - 1.f) / (e + 1.f);
}

__global__ __launch_bounds__(512, 2) void gemm_lstm(
    const unsigned short* __restrict__ Abf, const unsigned short* __restrict__ Wbf,
    const float* __restrict__ bias, const float* __restrict__ c,
    float* __restrict__ out)
{
    __shared__ __align__(16) unsigned short sh[32768];   // 64 KiB: 2 x A-tile

    const int tid  = threadIdx.x;
    const int lane = tid & 63;
    const int wid  = tid >> 6;
    const int wr   = wid >> 2;            // 0..1
    const int wc   = wid & 3;             // 0..3

    // L2-partitioned mapping: each XCD owns 2 B-panels (L2-resident 2 MB).
    const int bid  = blockIdx.x;
    const int xcd  = bid & 7;
    const int loc  = bid >> 3;            // 0..127
    const int nbk  = (xcd << 1) | (loc & 1);   // 0..15
    const int mbk  = loc >> 1;                 // 0..63
    const int brow = mbk << 8, bcol = nbk << 8;

    const int l15  = lane & 15;
    const int rA0  = (wr << 7) + l15;

    // B fragment global base pointers (k advances by 64 elems per tile)
    const unsigned short* bp[4];
#pragma unroll
    for (int n = 0; n < 4; ++n)
        bp[n] = Wbf + (size_t)(bcol + (wc << 6) + n * 16 + l15) * K
                    + ((lane >> 4) << 3);

    f32x4 acc[8][4];
#pragma unroll
    for (int i = 0; i < 8; ++i)
#pragma unroll
        for (int j = 0; j < 4; ++j) acc[i][j] = f32x4{0.f, 0.f, 0.f, 0.f};
    bf16x8 a[4][2], b[4][2];

    // prologue: stage A-tile0 (4 VM ops), drain, publish
    {
        stage_half(Abf, brow,       0, sh,        tid);
        stage_half(Abf, brow + 128, 0, sh + 8192, tid);
        asm volatile("s_waitcnt vmcnt(0)" ::: "memory");
        __builtin_amdgcn_s_barrier();
    }

    for (int t = 0; t < NT; ++t) {
        const int q = t & 1;
        unsigned short* curA = sh + q * 16384;
        unsigned short* nxtA = sh + (q ^ 1) * 16384;
        const int k1 = ((t + 1) & 31) << 6;   // wrapped tail: garbage into dead buf
        const int kg = t << 6;

        // stage A tile t+1 (4 VM ops; nxtA reads finished before (t-1)-end barrier)
        stage_half(Abf, brow,       k1, nxtA,        tid);
        stage_half(Abf, brow + 128, k1, nxtA + 8192, tid);

        // ---- B frags: global->register (VMEM pipe, L2-resident)
#pragma unroll
        for (int n = 0; n < 4; ++n)
#pragma unroll
            for (int ks = 0; ks < 2; ++ks)
                b[n][ks] = *(const bf16x8*)(bp[n] + kg + (ks << 5));

        // ---- A mh0 (8 LDS reads)
#pragma unroll
        for (int m = 0; m < 4; ++m)
#pragma unroll
            for (int ks = 0; ks < 2; ++ks)
                a[m][ks] = ldfrag(curA, rA0 + m * 16, ks, lane);

        // ---- MFMA mh0 (32)
#pragma unroll
        for (int ks = 0; ks < 2; ++ks)
#pragma unroll
            for (int m = 0; m < 4; ++m)
#pragma unroll
                for (int n = 0; n < 4; ++n)
                    acc[m][n] = __builtin_amdgcn_mfma_f32_16x16x32_bf16(
                        a[m][ks], b[n][ks], acc[m][n], 0, 0, 0);

        // ---- A mh1 (8 LDS reads, reuse regs)
#pragma unroll
        for (int m = 0; m < 4; ++m)
#pragma unroll
            for (int ks = 0; ks < 2; ++ks)
                a[m][ks] = ldfrag(curA, rA0 + 64 + m * 16, ks, lane);

        // ---- MFMA mh1 (32)
#pragma unroll
        for (int ks = 0; ks < 2; ++ks)
#pragma unroll
            for (int m = 0; m < 4; ++m)
#pragma unroll
                for (int n = 0; n < 4; ++n)
                    acc[4 + m][n] = __builtin_amdgcn_mfma_f32_16x16x32_bf16(
                        a[m][ks], b[n][ks], acc[4 + m][n], 0, 0, 0);

        // tile-end: publish A tile t+1 (staged a full tile ago) and release cur
        asm volatile("s_waitcnt vmcnt(0)" ::: "memory");
        __builtin_amdgcn_s_barrier();
    }

    // ---- fused LSTM epilogue: n-index = gate for one h-col per lane
    const int hcol  = (((nbk << 2) + wc) << 4) + l15;
    const int crow0 = brow + (wr << 7) + ((lane >> 4) << 2);
    const int cb0   = bcol + (wc << 6) + l15;
    const float bs0 = bias[cb0];
    const float bs1 = bias[cb0 + 16];
    const float bs2 = bias[cb0 + 32];
    const float bs3 = bias[cb0 + 48];
    const size_t P  = (size_t)B_ * H_;
#pragma unroll
    for (int mf = 0; mf < 8; ++mf) {
#pragma unroll
        for (int j = 0; j < 4; ++j) {
            const int row = crow0 + mf * 16 + j;
            const size_t base = (size_t)row * H_ + hcol;
            float fg = sigf(acc[mf][0][j] + bs0);
            float ig = sigf(acc[mf][1][j] + bs1);
            float kg = tanhfast(acc[mf][2][j] + bs2);
            float og = sigf(acc[mf][3][j] + bs3);
            float cv = c[base];
            float cn = fg * cv + ig * kg;
            float hn = og * tanhfast(cn);
            out[base]         = og;
            out[P + base]     = cn;
            out[2 * P + base] = hn;
        }
    }
}

// ---------------------------------------------------------------- launch
extern "C" void kernel_launch(void* const* d_in, const int* in_sizes, int n_in,
                              void* d_out, int out_size, void* d_ws, size_t ws_size,
                              hipStream_t stream)
{
    const float* x  = (const float*)d_in[0];
    const float* c  = (const float*)d_in[1];
    const float* h  = (const float*)d_in[2];
    const float* Wx = (const float*)d_in[3];
    const float* bx = (const float*)d_in[4];
    const float* Wh = (const float*)d_in[5];
    const float* bh = (const float*)d_in[6];

    unsigned short* Abf  = (unsigned short*)((char*)d_ws + OFF_A);
    unsigned short* Wbf  = (unsigned short*)((char*)d_ws + OFF_W);
    float*          bias = (float*)((char*)d_ws + OFF_BI);
    float*          out  = (float*)d_out;

    cvt_kernel<<<40960, 256, 0, stream>>>(x, h, Wx, Wh, Abf, Wbf);
    bias_kernel<<<16, 256, 0, stream>>>(bx, bh, bias);
    gemm_lstm<<<(M / 256) * (N / 256), 512, 0, stream>>>(
        Abf, Wbf, bias, c, out);
}

// Round 12
// 358.415 us; speedup vs baseline: 1.2768x; 1.2768x over previous
//
#include <hip/hip_runtime.h>
#include <hip/hip_bf16.h>
#include <cstdint>

#define DI __device__ __forceinline__

typedef __attribute__((ext_vector_type(4))) float f32x4;
typedef __attribute__((ext_vector_type(8))) short bf16x8;

static constexpr int B_ = 16384, I_ = 1024, H_ = 1024;
static constexpr int M = B_;          // 16384 rows
static constexpr int N = 4 * H_;      // 4096 gate-cols (permuted: see cvt)
static constexpr int K = I_ + H_;     // 2048 ([x | h])
static constexpr int NS = K / 32;     // 64 K-steps (BK=32)

// workspace layout (bytes)
static constexpr size_t OFF_A  = 0;                         // M*K bf16   (64 MB)
static constexpr size_t OFF_W  = OFF_A + (size_t)M * K * 2; // N*K bf16   (16 MB)
static constexpr size_t OFF_BI = OFF_W + (size_t)N * K * 2; // N f32      (16 KB)

DI unsigned short f2bf(float f) {
    union { float f; unsigned u; } v; v.f = f;
    unsigned r = v.u + 0x7FFFu + ((v.u >> 16) & 1u);
    return (unsigned short)(r >> 16);
}

// ---------------------------------------------------------------- convert
// A' = [x | h] (M x K) bf16. W' rows PERMUTED so that GEMM col
// r = g64*64 + gate*16 + l15 maps to (gate, hcol = g64*16 + l15).
__global__ void cvt_kernel(const float* __restrict__ x, const float* __restrict__ h,
                           const float* __restrict__ Wx, const float* __restrict__ Wh,
                           unsigned short* __restrict__ A, unsigned short* __restrict__ W)
{
    long tid = (long)blockIdx.x * blockDim.x + threadIdx.x;
    long row = tid >> 9;
    int  col = (int)(tid & 511) * 4;
    const float* src;
    unsigned short* dst;
    if (row < M) {
        src = (col < I_) ? x + (size_t)row * I_ + col
                         : h + (size_t)row * H_ + (col - I_);
        dst = A + (size_t)row * K + col;
    } else {
        int r = (int)(row - M);                 // dst row in W'
        int gate = (r >> 4) & 3;
        int hcol = ((r >> 6) << 4) | (r & 15);
        int srow = gate * H_ + hcol;            // src row in [4,H] stack
        src = (col < I_) ? Wx + (size_t)srow * I_ + col
                         : Wh + (size_t)srow * H_ + (col - I_);
        dst = W + (size_t)r * K + col;
    }
    float4 v = *(const float4*)src;
    ushort4 o;
    o.x = f2bf(v.x); o.y = f2bf(v.y); o.z = f2bf(v.z); o.w = f2bf(v.w);
    *(ushort4*)dst = o;
}

__global__ void bias_kernel(const float* __restrict__ bx, const float* __restrict__ bh,
                            float* __restrict__ bias)
{
    int r = blockIdx.x * blockDim.x + threadIdx.x;
    if (r < N) {
        int gate = (r >> 4) & 3;
        int hcol = ((r >> 6) << 4) | (r & 15);
        int s = gate * H_ + hcol;
        bias[r] = bx[s] + bh[s];
    }
}

// ---------------------------------------------------------------- GEMM 128x256
// BK=32, 8 waves (2M x 4N) of 64x64, acc = 64 VGPR -> <=128 regs/wave
// (launch_bounds(512,4)) -> 4 waves/SIMD; LDS 48 KB -> TWO independent
// blocks resident per CU. Independent barrier domains anti-phase naturally:
// while block0's waves burst MFMA, block1's drain LDS reads (m97/m114
// mechanism). Sync is minimal: one vmcnt(0)+barrier per K-step, pre-barrier
// (publishes all waves' staged data -- round-5 invariant).
//
// LDS swizzle (BK=32: 4 x 16B slots/row): stored slot s of row r holds
// global k-slot (s - (r>>1)) & 3; read side uses sl = (slot + (row>>1)) & 3.
// 16-lane fragment reads then spread across banks (<=2-way, free).
DI void stage_A(const unsigned short* __restrict__ g, int grow0, int kcol,
                unsigned short* ldsbase, int tid)
{
    const int w    = tid >> 6, lane = tid & 63;
    const int row  = grow0 + (w << 4) + (lane >> 2);
    const int kk   = kcol + ((((lane & 3) - ((lane >> 3) & 3)) & 3) << 3);
    const unsigned short* gp = g + (size_t)row * K + kk;
    unsigned short* lp = ldsbase + (w << 9);            // wave-uniform, linear
    __builtin_amdgcn_global_load_lds(
        (const __attribute__((address_space(1))) void*)gp,
        (__attribute__((address_space(3))) void*)lp, 16, 0, 0);
}

DI bf16x8 ldfrag(const unsigned short* tile, int row, int lane)
{
    const int sl = ((lane >> 4) + (row >> 1)) & 3;
    return *(const bf16x8*)(tile + (row << 5) + (sl << 3));
}

DI float sigf(float v) { return 1.f / (1.f + __expf(-v)); }
DI float tanhfast(float v) {
    float vc = fminf(fmaxf(v, -15.f), 15.f);
    float e  = __expf(2.f * vc);
    return (e - 1.f) / (e + 1.f);
}

__global__ __launch_bounds__(512, 4) void gemm_lstm(
    const unsigned short* __restrict__ Abf, const unsigned short* __restrict__ Wbf,
    const float* __restrict__ bias, const float* __restrict__ c,
    float* __restrict__ out)
{
    // A[q]=sh+q*4096 (128x32), B[q]=sh+8192+q*8192 (256x32): 48 KiB total
    __shared__ __align__(16) unsigned short sh[24576];

    const int tid  = threadIdx.x;
    const int lane = tid & 63;
    const int wid  = tid >> 6;
    const int wr   = wid >> 2;            // 0..1  (64-row slice)
    const int wc   = wid & 3;             // 0..3  (64-col slice)

    // XCD-partitioned mapping: grid 2048 = 8 x 256
    const int bid  = blockIdx.x;
    const int xcd  = bid & 7;
    const int loc  = bid >> 3;                 // 0..255
    const int nbk  = (xcd << 1) | (loc & 1);   // 0..15 (256-col panels)
    const int mbk  = loc >> 1;                 // 0..127 (128-row panels)
    const int brow = mbk << 7, bcol = nbk << 8;

    const int l15  = lane & 15;
    const int rA0  = (wr << 6) + l15;
    const int rB0  = (wc << 6) + l15;

    f32x4 acc[4][4];
#pragma unroll
    for (int i = 0; i < 4; ++i)
#pragma unroll
        for (int j = 0; j < 4; ++j) acc[i][j] = f32x4{0.f, 0.f, 0.f, 0.f};
    bf16x8 a[4], b[4];

    // prologue: stage step0 (3 VM ops), drain, publish
    {
        stage_A(Abf, brow,       0, sh,         tid);
        stage_A(Wbf, bcol,       0, sh + 8192,  tid);
        stage_A(Wbf, bcol + 128, 0, sh + 12288, tid);
        asm volatile("s_waitcnt vmcnt(0)" ::: "memory");
        __builtin_amdgcn_s_barrier();
    }

    for (int t = 0; t < NS; ++t) {
        const int q = t & 1;
        unsigned short* curA = sh + (q << 12);
        unsigned short* curB = sh + 8192 + (q << 13);
        unsigned short* nxtA = sh + ((q ^ 1) << 12);
        unsigned short* nxtB = sh + 8192 + ((q ^ 1) << 13);
        const int k1 = ((t + 1) & 63) << 5;   // wrapped tail: garbage into dead buf

        // stage step t+1 (nxt last read in step t-1; freed at its barrier)
        stage_A(Abf, brow,       k1, nxtA,        tid);
        stage_A(Wbf, bcol,       k1, nxtB,        tid);
        stage_A(Wbf, bcol + 128, k1, nxtB + 4096, tid);

        // frags: 4 A + 4 B ds_read_b128
#pragma unroll
        for (int m = 0; m < 4; ++m) a[m] = ldfrag(curA, rA0 + m * 16, lane);
#pragma unroll
        for (int n = 0; n < 4; ++n) b[n] = ldfrag(curB, rB0 + n * 16, lane);

        // 16 MFMA (K=32 consumed in one shot)
#pragma unroll
        for (int m = 0; m < 4; ++m)
#pragma unroll
            for (int n = 0; n < 4; ++n)
                acc[m][n] = __builtin_amdgcn_mfma_f32_16x16x32_bf16(
                    a[m], b[n], acc[m][n], 0, 0, 0);

        // step-end: publish t+1 stages (issued a full step ago) + release cur
        asm volatile("s_waitcnt vmcnt(0)" ::: "memory");
        __builtin_amdgcn_s_barrier();
    }

    // ---- fused LSTM epilogue: n-index = gate for one h-col per lane
    const int hcol  = (((nbk << 2) + wc) << 4) + l15;
    const int crow0 = brow + (wr << 6) + ((lane >> 4) << 2);
    const int cb0   = bcol + (wc << 6) + l15;
    const float bs0 = bias[cb0];
    const float bs1 = bias[cb0 + 16];
    const float bs2 = bias[cb0 + 32];
    const float bs3 = bias[cb0 + 48];
    const size_t P  = (size_t)B_ * H_;
#pragma unroll
    for (int mf = 0; mf < 4; ++mf) {
#pragma unroll
        for (int j = 0; j < 4; ++j) {
            const int row = crow0 + mf * 16 + j;
            const size_t base = (size_t)row * H_ + hcol;
            float fg = sigf(acc[mf][0][j] + bs0);
            float ig = sigf(acc[mf][1][j] + bs1);
            float kg = tanhfast(acc[mf][2][j] + bs2);
            float og = sigf(acc[mf][3][j] + bs3);
            float cv = c[base];
            float cn = fg * cv + ig * kg;
            float hn = og * tanhfast(cn);
            out[base]         = og;
            out[P + base]     = cn;
            out[2 * P + base] = hn;
        }
    }
}

// ---------------------------------------------------------------- launch
extern "C" void kernel_launch(void* const* d_in, const int* in_sizes, int n_in,
                              void* d_out, int out_size, void* d_ws, size_t ws_size,
                              hipStream_t stream)
{
    const float* x  = (const float*)d_in[0];
    const float* c  = (const float*)d_in[1];
    const float* h  = (const float*)d_in[2];
    const float* Wx = (const float*)d_in[3];
    const float* bx = (const float*)d_in[4];
    const float* Wh = (const float*)d_in[5];
    const float* bh = (const float*)d_in[6];

    unsigned short* Abf  = (unsigned short*)((char*)d_ws + OFF_A);
    unsigned short* Wbf  = (unsigned short*)((char*)d_ws + OFF_W);
    float*          bias = (float*)((char*)d_ws + OFF_BI);
    float*          out  = (float*)d_out;

    cvt_kernel<<<40960, 256, 0, stream>>>(x, h, Wx, Wh, Abf, Wbf);
    bias_kernel<<<16, 256, 0, stream>>>(bx, bh, bias);
    gemm_lstm<<<(M / 128) * (N / 256), 512, 0, stream>>>(
        Abf, Wbf, bias, c, out);
}

// Round 13
// 330.627 us; speedup vs baseline: 1.3841x; 1.0840x over previous
//
#include <hip/hip_runtime.h>
#include <hip/hip_bf16.h>
#include <cstdint>

#define DI __device__ __forceinline__

typedef __attribute__((ext_vector_type(4))) float f32x4;
typedef __attribute__((ext_vector_type(8))) short bf16x8;

static constexpr int B_ = 16384, I_ = 1024, H_ = 1024;
static constexpr int M = B_;          // 16384 rows
static constexpr int N = 4 * H_;      // 4096 gate-cols (permuted)
static constexpr int K = I_ + H_;     // 2048 ([x | h])
static constexpr int NT = K / 64;     // 32 K-tiles

// workspace layout (bytes)
static constexpr size_t OFF_A  = 0;                         // M*K bf16   (64 MB)
static constexpr size_t OFF_W  = OFF_A + (size_t)M * K * 2; // W2 frag-layout (16 MB)
static constexpr size_t OFF_BI = OFF_W + (size_t)N * K * 2; // N f32      (16 KB)

DI unsigned short f2bf(float f) {
    union { float f; unsigned u; } v; v.f = f;
    unsigned r = v.u + 0x7FFFu + ((v.u >> 16) & 1u);
    return (unsigned short)(r >> 16);
}

// ---------------------------------------------------------------- convert A
// A' = [x | h] (M x K) bf16, row-major.
__global__ void cvt_a(const float* __restrict__ x, const float* __restrict__ h,
                      unsigned short* __restrict__ A)
{
    long tid = (long)blockIdx.x * blockDim.x + threadIdx.x;
    long row = tid >> 9;               // 512 groups of 4 cols (K=2048)
    int  col = (int)(tid & 511) * 4;
    const float* src = (col < I_) ? x + (size_t)row * I_ + col
                                  : h + (size_t)row * H_ + (col - I_);
    float4 v = *(const float4*)src;
    ushort4 o;
    o.x = f2bf(v.x); o.y = f2bf(v.y); o.z = f2bf(v.z); o.w = f2bf(v.w);
    *(ushort4*)(A + (size_t)row * K + col) = o;
}

// ---------------------------------------------------------------- convert W2
// W2 = weights in MFMA B-fragment layout. GEMM column space is gate-permuted:
// col c = g64*64 + gate*16 + hcol16  (gate = (c>>4)&3, hcol = (c>>6)*16+(c&15)).
// Fragment chunk (f, s, lane) [f = c>>4 (0..255), s = kstep (0..63)] holds
// W'[f*16 + (lane&15)][s*32 + (lane>>4)*8 .. +7], so a wave's B-frag load is
// 64 lanes x 16B contiguous (1 KB).
__global__ void cvt_w2(const float* __restrict__ Wx, const float* __restrict__ Wh,
                       unsigned short* __restrict__ W2)
{
    int tid  = blockIdx.x * blockDim.x + threadIdx.x;   // 1,048,576 threads
    int lane = tid & 63;
    int s    = (tid >> 6) & 63;
    int f    = tid >> 12;               // 0..255
    int col16 = lane & 15;
    int gate  = f & 3;
    int hcol  = ((f >> 2) << 4) | col16;
    int srow  = gate * H_ + hcol;       // row in the [4,H] weight stack
    int k0    = (s << 5) + ((lane >> 4) << 3);   // 0..2040, multiple of 8

    const float* p = (k0 < I_) ? Wx + (size_t)srow * I_ + k0
                               : Wh + (size_t)srow * H_ + (k0 - I_);
    float4 v0 = *(const float4*)p;
    float4 v1 = *(const float4*)(p + 4);
    unsigned short o[8] = { f2bf(v0.x), f2bf(v0.y), f2bf(v0.z), f2bf(v0.w),
                            f2bf(v1.x), f2bf(v1.y), f2bf(v1.z), f2bf(v1.w) };
    *(ushort4*)(W2 + (((size_t)f * 64 + s) << 9) + (lane << 3))     = *(ushort4*)&o[0];
    *(ushort4*)(W2 + (((size_t)f * 64 + s) << 9) + (lane << 3) + 4) = *(ushort4*)&o[4];
}

__global__ void bias_kernel(const float* __restrict__ bx, const float* __restrict__ bh,
                            float* __restrict__ bias)
{
    int r = blockIdx.x * blockDim.x + threadIdx.x;
    if (r < N) {
        int gate = (r >> 4) & 3;
        int hcol = ((r >> 6) << 4) | (r & 15);
        int s = gate * H_ + hcol;
        bias[r] = bx[s] + bh[s];
    }
}

// ---------------------------------------------------------------- GEMM 256x256
// A: LDS-staged (global_load_lds, swizzled), double-buffered 2x32KB.
// B: DIRECT global->register fragment loads from W2 (coalesced 1KB/wave,
// L2-resident 2MB/XCD with the partitioned mapping) -- B never touches LDS.
// Per-tile LDS traffic drops 196KB -> 128KB reads + 32KB writes; the B
// stream rides the VMEM pipe. One vmcnt(0)+barrier per K-tile (round-5
// pre-barrier publication invariant).
DI void stage_half(const unsigned short* __restrict__ g, int grow0, int kcol,
                   unsigned short* ldsbase, int tid)
{
    const int w    = tid >> 6, lane = tid & 63;
    const int rsub = (w << 3) + (lane >> 3);
    const int kk   = kcol + (((lane & 7) ^ (lane >> 3)) << 3);  // inverse-swizzled src
#pragma unroll
    for (int l = 0; l < 2; ++l) {
        const unsigned short* gp = g + (size_t)(grow0 + (l << 6) + rsub) * K + kk;
        unsigned short* lp = ldsbase + (((l << 6) + (w << 3)) << 6);
        __builtin_amdgcn_global_load_lds(
            (const __attribute__((address_space(1))) void*)gp,
            (__attribute__((address_space(3))) void*)lp, 16, 0, 0);
    }
}

DI bf16x8 ldfrag(const unsigned short* tile, int row, int ks, int lane)
{
    const int sl = ((ks << 2) + (lane >> 4)) ^ (lane & 7);
    return *(const bf16x8*)(tile + (row << 6) + (sl << 3));
}

DI float sigf(float v) { return 1.f / (1.f + __expf(-v)); }
DI float tanhfast(float v) {
    float vc = fminf(fmaxf(v, -15.f), 15.f);
    float e  = __expf(2.f * vc);
    return (e - 1.f) / (e + 1.f);
}

__global__ __launch_bounds__(512, 2) void gemm_lstm(
    const unsigned short* __restrict__ Abf, const unsigned short* __restrict__ W2,
    const float* __restrict__ bias, const float* __restrict__ c,
    float* __restrict__ out)
{
    __shared__ __align__(16) unsigned short sh[32768];   // 64 KiB: 2 x A-tile

    const int tid  = threadIdx.x;
    const int lane = tid & 63;
    const int wid  = tid >> 6;
    const int wr   = wid >> 2;            // 0..1
    const int wc   = wid & 3;             // 0..3

    // XCD-partitioned mapping: each XCD owns 2 B-panels (W2-slice 2MB, L2-fit)
    const int bid  = blockIdx.x;
    const int xcd  = bid & 7;
    const int loc  = bid >> 3;            // 0..127
    const int nbk  = (xcd << 1) | (loc & 1);   // 0..15
    const int mbk  = loc >> 1;                 // 0..63
    const int brow = mbk << 8, bcol = nbk << 8;

    const int l15  = lane & 15;
    const int rA0  = (wr << 7) + l15;
    const int nf0  = (bcol >> 4) + (wc << 2);   // first B-fragment index

    // per-lane W2 pointer: chunk(f, s) at (f*64+s)*512 + lane*8 shorts
    const unsigned short* w2p = W2 + (lane << 3);

    f32x4 acc[8][4];
#pragma unroll
    for (int i = 0; i < 8; ++i)
#pragma unroll
        for (int j = 0; j < 4; ++j) acc[i][j] = f32x4{0.f, 0.f, 0.f, 0.f};
    bf16x8 a[4][2], b[4][2];

    // prologue: stage A-tile0, drain, publish
    {
        stage_half(Abf, brow,       0, sh,        tid);
        stage_half(Abf, brow + 128, 0, sh + 8192, tid);
        asm volatile("s_waitcnt vmcnt(0)" ::: "memory");
        __builtin_amdgcn_s_barrier();
    }

    for (int t = 0; t < NT; ++t) {
        const int q = t & 1;
        unsigned short* curA = sh + (q << 14);
        unsigned short* nxtA = sh + ((q ^ 1) << 14);
        const int k1 = ((t + 1) & 31) << 6;   // wrapped tail: garbage into dead buf

        // stage A tile t+1 (4 VM ops)
        stage_half(Abf, brow,       k1, nxtA,        tid);
        stage_half(Abf, brow + 128, k1, nxtA + 8192, tid);

        // ---- B frags: coalesced global->register from W2 (VMEM pipe)
#pragma unroll
        for (int n = 0; n < 4; ++n)
#pragma unroll
            for (int ks = 0; ks < 2; ++ks)
                b[n][ks] = *(const bf16x8*)(
                    w2p + (((size_t)(nf0 + n) * 64 + (t << 1) + ks) << 9));

        // ---- A mh0 (8 LDS reads)
#pragma unroll
        for (int m = 0; m < 4; ++m)
#pragma unroll
            for (int ks = 0; ks < 2; ++ks)
                a[m][ks] = ldfrag(curA, rA0 + m * 16, ks, lane);

        // ---- MFMA mh0 (32)
#pragma unroll
        for (int ks = 0; ks < 2; ++ks)
#pragma unroll
            for (int m = 0; m < 4; ++m)
#pragma unroll
                for (int n = 0; n < 4; ++n)
                    acc[m][n] = __builtin_amdgcn_mfma_f32_16x16x32_bf16(
                        a[m][ks], b[n][ks], acc[m][n], 0, 0, 0);

        // ---- A mh1 (8 LDS reads, reuse regs)
#pragma unroll
        for (int m = 0; m < 4; ++m)
#pragma unroll
            for (int ks = 0; ks < 2; ++ks)
                a[m][ks] = ldfrag(curA, rA0 + 64 + m * 16, ks, lane);

        // ---- MFMA mh1 (32)
#pragma unroll
        for (int ks = 0; ks < 2; ++ks)
#pragma unroll
            for (int m = 0; m < 4; ++m)
#pragma unroll
                for (int n = 0; n < 4; ++n)
                    acc[4 + m][n] = __builtin_amdgcn_mfma_f32_16x16x32_bf16(
                        a[m][ks], b[n][ks], acc[4 + m][n], 0, 0, 0);

        // tile-end: publish A tile t+1 (staged a full tile ago) + release cur
        asm volatile("s_waitcnt vmcnt(0)" ::: "memory");
        __builtin_amdgcn_s_barrier();
    }

    // ---- fused LSTM epilogue: n-index = gate for one h-col per lane
    const int hcol  = (((nbk << 2) + wc) << 4) + l15;
    const int crow0 = brow + (wr << 7) + ((lane >> 4) << 2);
    const int cb0   = bcol + (wc << 6) + l15;
    const float bs0 = bias[cb0];
    const float bs1 = bias[cb0 + 16];
    const float bs2 = bias[cb0 + 32];
    const float bs3 = bias[cb0 + 48];
    const size_t P  = (size_t)B_ * H_;
#pragma unroll
    for (int mf = 0; mf < 8; ++mf) {
#pragma unroll
        for (int j = 0; j < 4; ++j) {
            const int row = crow0 + mf * 16 + j;
            const size_t base = (size_t)row * H_ + hcol;
            float fg = sigf(acc[mf][0][j] + bs0);
            float ig = sigf(acc[mf][1][j] + bs1);
            float kg = tanhfast(acc[mf][2][j] + bs2);
            float og = sigf(acc[mf][3][j] + bs3);
            float cv = c[base];
            float cn = fg * cv + ig * kg;
            float hn = og * tanhfast(cn);
            out[base]         = og;
            out[P + base]     = cn;
            out[2 * P + base] = hn;
        }
    }
}

// ---------------------------------------------------------------- launch
extern "C" void kernel_launch(void* const* d_in, const int* in_sizes, int n_in,
                              void* d_out, int out_size, void* d_ws, size_t ws_size,
                              hipStream_t stream)
{
    const float* x  = (const float*)d_in[0];
    const float* c  = (const float*)d_in[1];
    const float* h  = (const float*)d_in[2];
    const float* Wx = (const float*)d_in[3];
    const float* bx = (const float*)d_in[4];
    const float* Wh = (const float*)d_in[5];
    const float* bh = (const float*)d_in[6];

    unsigned short* Abf  = (unsigned short*)((char*)d_ws + OFF_A);
    unsigned short* W2   = (unsigned short*)((char*)d_ws + OFF_W);
    float*          bias = (float*)((char*)d_ws + OFF_BI);
    float*          out  = (float*)d_out;

    cvt_a<<<(M * 512) / 256, 256, 0, stream>>>(x, h, Abf);
    cvt_w2<<<4096, 256, 0, stream>>>(Wx, Wh, W2);
    bias_kernel<<<16, 256, 0, stream>>>(bx, bh, bias);
    gemm_lstm<<<(M / 256) * (N / 256), 512, 0, stream>>>(
        Abf, W2, bias, c, out);
}